// Round 1
// baseline (152.774 us; speedup 1.0000x reference)
//
#include <hip/hip_runtime.h>
#include <hip/hip_bf16.h>
#include <cmath>

#define B_   4
#define NT_  2048
#define G_   4096
#define DZ_  128
#define BK_  64

typedef __attribute__((ext_vector_type(8))) short bf16x8;
typedef __attribute__((ext_vector_type(4))) float f32x4;

__device__ __forceinline__ float softplus_f(float x) {
    return fmaxf(x, 0.0f) + log1pf(expf(-fabsf(x)));
}

// z_grid (B,G,DZ) fp32 -> Zt (B,DZ,G) bf16 (RNE)
__global__ __launch_bounds__(256, 1)
void transpose_z(const float* __restrict__ z, unsigned short* __restrict__ zt)
{
    __shared__ unsigned short tile[64][66];   // +2 ushort pad: 2-way bank alias only
    const int bx = blockIdx.x;                // 4b * 64gt * 2zt = 512
    const int zti = bx & 1;
    const int gt  = (bx >> 1) & 63;
    const int b   = bx >> 7;
    const int g0 = gt * 64, z0 = zti * 64;
    const int tid = threadIdx.x;
    const int zl = tid & 63, gl = tid >> 6;
    #pragma unroll
    for (int i = 0; i < 16; ++i) {
        const int g = gl + i * 4;
        const float v = z[(size_t)(b * G_ + g0 + g) * DZ_ + z0 + zl];
        unsigned int u = __float_as_uint(v);
        u = u + 0x7FFFu + ((u >> 16) & 1u);   // round-nearest-even to bf16
        tile[g][zl] = (unsigned short)(u >> 16);
    }
    __syncthreads();
    const int gl2 = tid & 63, zl2 = tid >> 6;
    #pragma unroll
    for (int i = 0; i < 16; ++i) {
        const int zz = zl2 + i * 4;
        zt[(size_t)(b * DZ_ + z0 + zz) * G_ + g0 + gl2] = tile[gl2][zz];
    }
}

// Fused: weights computed in-register in MFMA A-layout; Zt staged in LDS as B-frags.
// Block: (b, 64 t, 64 z, both NK). Wave: m-tile = wave, 4 n-tiles, both kk.
__global__ __launch_bounds__(256, 1)
void setconv_main(const float* __restrict__ xt,
                  const float* __restrict__ xg,
                  const float* __restrict__ lsp,
                  const unsigned short* __restrict__ Zt,
                  float* __restrict__ out)
{
    __shared__ unsigned short ldsZ[64 * 72];  // 64 z-rows x (64 data + 8 pad) ushorts

    const int bx   = blockIdx.x;              // 256 = 4b * 32tt * 2zh
    const int zh   = bx & 1;
    const int tt   = (bx >> 1) & 31;
    const int b    = bx >> 6;
    const int tid  = threadIdx.x;
    const int wave = tid >> 6;
    const int lane = tid & 63;
    const int l15  = lane & 15;
    const int quad = lane >> 4;

    const int t0 = tt * 64;
    const int z0 = zh * 64;

    // c[d][k] = -0.5*log2(e)/ls_dk^2  (exp(-0.5*s) == exp2(sum q_d * c_dk))
    float c00, c01, c10, c11;
    {
        const float h = -0.72134752f;         // -0.5*log2(e)
        float p, ls;
        p = lsp[0]; ls = 1e-5f + softplus_f(p); c00 = h / (ls * ls);
        p = lsp[1]; ls = 1e-5f + softplus_f(p); c01 = h / (ls * ls);
        p = lsp[2]; ls = 1e-5f + softplus_f(p); c10 = h / (ls * ls);
        p = lsp[3]; ls = 1e-5f + softplus_f(p); c11 = h / (ls * ls);
    }

    // this lane's A-frag row: m = lane&15
    const int trow = t0 + wave * 16 + l15;
    const float xt0 = xt[(size_t)(b * NT_ + trow) * 2 + 0];
    const float xt1 = xt[(size_t)(b * NT_ + trow) * 2 + 1];

    f32x4 acc[2][4];
    #pragma unroll
    for (int k = 0; k < 2; ++k)
        #pragma unroll
        for (int n = 0; n < 4; ++n) acc[k][n] = (f32x4)0.0f;

    // staging: wave stages z-rows [wave*16, wave*16+16)
    const int sr0 = wave * 16 + (lane >> 3);
    const int sc  = (lane & 7) * 8;           // ushort col (16B per lane)
    const unsigned short* gz0 = Zt + (size_t)(b * DZ_ + z0 + sr0) * G_ + sc;
    const unsigned short* gz1 = gz0 + (size_t)8 * G_;
    const int lw0 = sr0 * 72 + sc;
    const int lw1 = (sr0 + 8) * 72 + sc;

    const float* xgq = xg + (size_t)(b * G_ + quad * 8) * 2;

    // prefetch chunk 0
    uint4 p0 = *(const uint4*)gz0;
    uint4 p1 = *(const uint4*)gz1;

    for (int ch = 0; ch < 64; ++ch) {
        __syncthreads();                      // all waves done reading prev tile
        *(uint4*)(&ldsZ[lw0]) = p0;
        *(uint4*)(&ldsZ[lw1]) = p1;
        __syncthreads();
        if (ch < 63) {                        // prefetch next chunk during compute
            p0 = *(const uint4*)(gz0 + (size_t)(ch + 1) * BK_);
            p1 = *(const uint4*)(gz1 + (size_t)(ch + 1) * BK_);
        }
        const int gbase = ch * BK_;
        #pragma unroll
        for (int s = 0; s < 2; ++s) {
            // B fragments: lane n=lane&15 holds k=quad*8+j (contiguous g in Zt row)
            bf16x8 bz[4];
            #pragma unroll
            for (int nt = 0; nt < 4; ++nt) {
                const int idx = (nt * 16 + l15) * 72 + s * 32 + quad * 8;
                bz[nt] = *(const bf16x8*)(&ldsZ[idx]);
            }
            // xg for this quad's 8 k-slots (broadcast within quad, L1-hot)
            const float* xp = xgq + (size_t)(gbase + s * 32) * 2;
            const float4 xv0 = *(const float4*)(xp + 0);
            const float4 xv1 = *(const float4*)(xp + 4);
            const float4 xv2 = *(const float4*)(xp + 8);
            const float4 xv3 = *(const float4*)(xp + 12);
            float gx[8], gy[8];
            gx[0]=xv0.x; gy[0]=xv0.y; gx[1]=xv0.z; gy[1]=xv0.w;
            gx[2]=xv1.x; gy[2]=xv1.y; gx[3]=xv1.z; gy[3]=xv1.w;
            gx[4]=xv2.x; gy[4]=xv2.y; gx[5]=xv2.z; gy[5]=xv2.w;
            gx[6]=xv3.x; gy[6]=xv3.y; gx[7]=xv3.z; gy[7]=xv3.w;
            unsigned int w0b[8], w1b[8];
            #pragma unroll
            for (int j = 0; j < 8; ++j) {
                const float d0 = xt0 - gx[j];
                const float d1 = xt1 - gy[j];
                const float q0 = d0 * d0;
                const float q1 = d1 * d1;
                const float e0 = fmaf(q1, c10, q0 * c00);
                const float e1 = fmaf(q1, c11, q0 * c01);
                w0b[j] = __float_as_uint(__builtin_amdgcn_exp2f(e0));
                w1b[j] = __float_as_uint(__builtin_amdgcn_exp2f(e1));
            }
            // pack hi16 of fp32 pairs -> bf16x2 (truncate; error << tolerance)
            union { bf16x8 v; unsigned int u[4]; } a0, a1;
            #pragma unroll
            for (int h = 0; h < 4; ++h) {
                a0.u[h] = __builtin_amdgcn_perm(w0b[2*h+1], w0b[2*h], 0x07060302u);
                a1.u[h] = __builtin_amdgcn_perm(w1b[2*h+1], w1b[2*h], 0x07060302u);
            }
            #pragma unroll
            for (int nt = 0; nt < 4; ++nt) {
                acc[0][nt] = __builtin_amdgcn_mfma_f32_16x16x32_bf16(a0.v, bz[nt], acc[0][nt], 0, 0, 0);
                acc[1][nt] = __builtin_amdgcn_mfma_f32_16x16x32_bf16(a1.v, bz[nt], acc[1][nt], 0, 0, 0);
            }
        }
    }

    // epilogue: C/D layout col=lane&15 (z), row=quad*4+r (t); pack (kk0,kk1) as float2
    const int trb = t0 + wave * 16 + quad * 4;
    #pragma unroll
    for (int nt = 0; nt < 4; ++nt) {
        const int zz = z0 + nt * 16 + l15;
        #pragma unroll
        for (int r = 0; r < 4; ++r) {
            float2 v = make_float2(acc[0][nt][r], acc[1][nt][r]);
            *(float2*)(out + (size_t)(b * NT_ + trb + r) * (DZ_ * 2) + zz * 2) = v;
        }
    }
}

extern "C" void kernel_launch(void* const* d_in, const int* in_sizes, int n_in,
                              void* d_out, int out_size, void* d_ws, size_t ws_size,
                              hipStream_t stream)
{
    const float* x_grid = (const float*)d_in[0];   // (4,64,64,2)
    const float* z_grid = (const float*)d_in[1];   // (4,64,64,128)
    const float* xt     = (const float*)d_in[2];   // (4,2048,2)
    const float* lsp    = (const float*)d_in[3];   // (2,2)
    float* out = (float*)d_out;                    // (4,2048,256) fp32
    unsigned short* Zt = (unsigned short*)d_ws;    // (4,128,4096) bf16 = 4 MB

    hipLaunchKernelGGL(transpose_z, dim3(512), dim3(256), 0, stream, z_grid, Zt);
    hipLaunchKernelGGL(setconv_main, dim3(256), dim3(256), 0, stream,
                       xt, x_grid, lsp, Zt, out);
}